// Round 5
// baseline (102.800 us; speedup 1.0000x reference)
//
#include <hip/hip_runtime.h>
#include <stdint.h>

typedef uint16_t u16;
typedef __attribute__((ext_vector_type(8))) short    bf16x8;  // 8 bf16 (4 VGPRs)
typedef __attribute__((ext_vector_type(8))) uint16_t u16x8;
typedef __attribute__((ext_vector_type(4))) float    f32x4;

#define B_    2
#define N_    100000
#define K_    26
#define CIN_  32
#define COUT_ 32

#define XT_ROWS  (N_ + 1)
// xt2: [2][B][XT_ROWS][16] bf16 rows of 32B; per (h,b) table = 3.2MB (L2-resident)
#define XT2_BYTES ((size_t)2 * B_ * XT_ROWS * 16 * 2)   // 12,800,128 bytes
// Wb2: [2][32][26][16] bf16 (h, o, k, ch) = 26624 elems
#define W_ELEMS  (2 * 32 * 26 * 16)

// ---- prep kernel geometry ----
#define TCHUNK      64
#define TBLK_PER_B  ((N_ + TCHUNK - 1) / TCHUNK)     // 1563
#define TBLKS       (B_ * TBLK_PER_B)                // 3126
#define WBLKS       13                               // 13 * 256 chunks = 3328 = 26624/8
#define PREP_GRID   (TBLKS + 1 + WBLKS)

// ---- conv kernel geometry ----
#define NPB         128                              // nodes per block (4 waves x 32)
#define CBLK_PER_B  ((N_ + NPB - 1) / NPB)           // 782
#define SLOTS       ((CBLK_PER_B + 3) / 4)           // 196 slots per XCD-half
#define CONV_GRID   (SLOTS * 8)                      // 1568

__device__ __forceinline__ u16 f2bf(float f) {
    union { float f; uint32_t u; } v; v.f = f;
    return (u16)((v.u + 0x7FFFu + ((v.u >> 16) & 1u)) >> 16);  // RNE
}

// Transpose inp [B][CIN][N] f32 -> xt2 [2][B][N+1][16] bf16 (32B rows),
// fill row at n==N, W -> Wb2 [2][32][26][16] bf16.
__global__ __launch_bounds__(256) void prep_kernel(
    const float* __restrict__ inp, const float* __restrict__ W,
    const float* __restrict__ fill, u16* __restrict__ xt2, u16* __restrict__ Wb2)
{
    int tid = threadIdx.x;
    int blk = blockIdx.x;
    if (blk >= TBLKS) {
        int job = blk - TBLKS;
        if (job == 0) {
            if (tid < 64) {
                int h = tid >> 5, b = (tid >> 4) & 1, c = tid & 15;
                xt2[((size_t)(h * B_ + b) * XT_ROWS + N_) * 16 + c] = f2bf(fill[h * 16 + c]);
            }
        } else {
            int i = (job - 1) * 256 + tid;            // chunk of 8 bf16; 3328 total
            int c8 = i & 1;
            int t  = i >> 1;
            int k  = t % 26;
            int t2 = t / 26;
            int o  = t2 & 31;
            int h  = t2 >> 5;
            const float* src = W + o * 832 + k * 32 + h * 16 + c8 * 8;  // 32B aligned
            float4 x = ((const float4*)src)[0], y = ((const float4*)src)[1];
            u16x8 v;
            v[0] = f2bf(x.x); v[1] = f2bf(x.y); v[2] = f2bf(x.z); v[3] = f2bf(x.w);
            v[4] = f2bf(y.x); v[5] = f2bf(y.y); v[6] = f2bf(y.z); v[7] = f2bf(y.w);
            *(u16x8*)(Wb2 + (size_t)i * 8) = v;
        }
        return;
    }
    __shared__ u16 tile[64][40];                      // pad: rows 80B
    int b  = blk / TBLK_PER_B;
    int n0 = (blk % TBLK_PER_B) * TCHUNK;
    const float* inb = inp + (size_t)b * CIN_ * N_;
    #pragma unroll
    for (int it = 0; it < 8; ++it) {
        int idx = it * 256 + tid;
        int c = idx >> 6, n = idx & 63;
        if (n0 + n < N_) tile[n][c] = f2bf(inb[(size_t)c * N_ + n0 + n]);
    }
    __syncthreads();
    int n = tid >> 2, seg = tid & 3;                  // seg: (h = seg>>1, c8 = seg&1)
    if (n0 + n < N_) {
        u16x8 v = *(const u16x8*)&tile[n][seg * 8];
        int h = seg >> 1, c8 = seg & 1;
        *(u16x8*)(xt2 + ((size_t)(h * B_ + b) * XT_ROWS + n0 + n) * 16 + c8 * 8) = v;
    }
}

#define MFMA16(a, b, c) __builtin_amdgcn_mfma_f32_16x16x32_bf16((a), (b), (c), 0, 0, 0)

// Gather + MFMA GEMM, channel-split two-phase (per-phase gather table 3.2MB -> L2).
// K=32 MFMA step = 2 neighbours x 16 ch. Lane group g: (nbr parity g>>1, ch chunk g&1).
// A = W (o = lane&15), B = feats (node = lane&15). Wave = 2 node-tiles x 16.
// Block swizzle: batch 0 -> XCDs 0-3, batch 1 -> XCDs 4-7.
__global__ __launch_bounds__(256, 5) void conv_kernel(
    const u16* __restrict__ xt2, const u16* __restrict__ Wb2,
    const int* __restrict__ nbr, const float* __restrict__ bias,
    float* __restrict__ out)
{
    int tid  = threadIdx.x;
    int bid  = blockIdx.x;
    int xcd  = bid & 7, slot = bid >> 3;
    int b    = xcd >> 2;
    int local = slot * 4 + (xcd & 3);
    if (local >= CBLK_PER_B) return;
    int node0 = local * NPB;
    int lane = tid & 63;
    int wv   = tid >> 6;
    int l15  = lane & 15, g = lane >> 4;
    int gsel = g >> 1, c8 = g & 1;

    const int* nbb  = nbr + (size_t)b * N_ * K_;
    float*     outb = out + (size_t)b * COUT_ * N_;

    int nbase = node0 + wv * 32;
    int n0c = nbase + l15;        if (n0c >= N_) n0c = N_ - 1;   // clamp tail
    int n1c = nbase + 16 + l15;   if (n1c >= N_) n1c = N_ - 1;
    const int* p0 = nbb + (size_t)n0c * K_;   // 104B rows -> int2 aligned
    const int* p1 = nbb + (size_t)n1c * K_;

    f32x4 acc[2][2];
    acc[0][0] = 0.0f; acc[0][1] = 0.0f; acc[1][0] = 0.0f; acc[1][1] = 0.0f;

    #pragma unroll 1
    for (int h = 0; h < 2; ++h) {                     // temporal phase per channel-half
        const u16* xg  = xt2 + (size_t)(h * B_ + b) * XT_ROWS * 16 + c8 * 8;
        const u16* wg0 = Wb2 + ((size_t)(h * 32 + l15) * 26 + gsel) * 16 + c8 * 8;
        #pragma unroll
        for (int kp = 0; kp < 13; ++kp) {             // 2 neighbours per iter
            bf16x8 a0 = *(const bf16x8*)(wg0 + kp * 32);              // o = l15
            bf16x8 a1 = *(const bf16x8*)(wg0 + 16 * 26 * 16 + kp * 32); // o = l15+16
            int2 v0 = *(const int2*)(p0 + 2 * kp);
            int2 v1 = *(const int2*)(p1 + 2 * kp);
            uint32_t i0 = (uint32_t)(gsel ? v0.y : v0.x);
            uint32_t i1 = (uint32_t)(gsel ? v1.y : v1.x);
            bf16x8 f0 = *(const bf16x8*)(xg + (i0 << 4));             // 32B row / 2 lanes
            bf16x8 f1 = *(const bf16x8*)(xg + (i1 << 4));
            acc[0][0] = MFMA16(a0, f0, acc[0][0]);
            acc[0][1] = MFMA16(a1, f0, acc[0][1]);
            acc[1][0] = MFMA16(a0, f1, acc[1][0]);
            acc[1][1] = MFMA16(a1, f1, acc[1][1]);
        }
        __syncthreads();                              // align waves between phases
    }

    float bs0[4], bs1[4];
    #pragma unroll
    for (int r = 0; r < 4; ++r) {
        bs0[r] = bias[g * 4 + r];
        bs1[r] = bias[g * 4 + r + 16];
    }
    #pragma unroll
    for (int t = 0; t < 2; ++t) {
        int node = nbase + t * 16 + l15;              // D col = lane&15 -> node
        if (node < N_) {
            #pragma unroll
            for (int r = 0; r < 4; ++r) {             // D row = g*4 + r -> o
                outb[(size_t)(g * 4 + r) * N_ + node]      = acc[t][0][r] + bs0[r];
                outb[(size_t)(g * 4 + r + 16) * N_ + node] = acc[t][1][r] + bs1[r];
            }
        }
    }
}

extern "C" void kernel_launch(void* const* d_in, const int* in_sizes, int n_in,
                              void* d_out, int out_size, void* d_ws, size_t ws_size,
                              hipStream_t stream) {
    (void)in_sizes; (void)n_in; (void)out_size; (void)ws_size;
    const float* inp  = (const float*)d_in[0];
    const int*   nbr  = (const int*)d_in[1];
    const float* W    = (const float*)d_in[2];
    const float* bias = (const float*)d_in[3];
    const float* fill = (const float*)d_in[4];
    float* out = (float*)d_out;

    u16* xt2 = (u16*)d_ws;                             // [2][B][N+1][16] bf16
    u16* Wb2 = (u16*)((char*)d_ws + XT2_BYTES);        // [2][32][26][16] bf16

    prep_kernel<<<PREP_GRID, 256, 0, stream>>>(inp, W, fill, xt2, Wb2);
    conv_kernel<<<CONV_GRID, 256, 0, stream>>>(xt2, Wb2, nbr, bias, out);
}